// Round 4
// baseline (371.207 us; speedup 1.0000x reference)
//
#include <hip/hip_runtime.h>

typedef float fvec4 __attribute__((ext_vector_type(4)));
typedef float f32x4 __attribute__((ext_vector_type(4)));
typedef short bf16x8 __attribute__((ext_vector_type(8)));

#define D   128   // D_IN == D_OUT
#define CAP 32    // per-direction adjacency slots (deg ~ Poisson(6), max ~25)

static __device__ __forceinline__ unsigned bcu(float f) {
    return __builtin_bit_cast(unsigned, f);
}
// pack two fp32 (round-half-up to bf16) into one u32 (lo elem in low half)
static __device__ __forceinline__ unsigned pack_bf2(float f0, float f1) {
    unsigned a0 = bcu(f0) + 0x8000u;
    unsigned a1 = bcu(f1) + 0x8000u;
    return __builtin_amdgcn_perm(a1, a0, 0x07060302u);
}
// full-precision RNE for the (tiny) weight prep
static __device__ __forceinline__ unsigned short f2bf_rne(float f) {
    unsigned u = bcu(f);
    u += 0x7FFFu + ((u >> 16) & 1u);
    return (unsigned short)(u >> 16);
}
static __device__ __forceinline__ float bflo(unsigned u) {
    return __builtin_bit_cast(float, u << 16);
}
static __device__ __forceinline__ float bfhi(unsigned u) {
    return __builtin_bit_cast(float, u & 0xFFFF0000u);
}

// ---------------------------------------------------------------------------
// P0: plain transposed weight triple Wt (bf16). NO swizzle -- rounds 0-3
// staged W through LDS (needed the swizzle for conflict-free ds_read), but
// LDS staging capped occupancy at 4-5 blocks/CU for BOTH latency-bound
// phases (atomic fill, random gather). MFMA is <1% utilized, so W operands
// now come straight from L2 (Wt = 96 KB, read by every block -> L2-hot).
// Wt[p][j][k] = W_p[k][j]  (j = output col, k = input row).
// p=0 -> W_s (K1), p=1 -> W_f, p=2 -> W_b (K2).
// ---------------------------------------------------------------------------
__global__ __launch_bounds__(256) void prep_w(
    const float* __restrict__ Wf, const float* __restrict__ Wb,
    const float* __restrict__ Ws, unsigned short* __restrict__ Wt)
{
    int t = blockIdx.x * 256 + threadIdx.x;
    if (t >= 3 * 128 * 128) return;
    int p = t >> 14;
    int e = t & 16383;
    int j = e >> 7;
    int k = e & 127;
    const float* W = (p == 0) ? Ws : (p == 1) ? Wf : Wb;
    Wt[t] = f2bf_rne(W[k * D + j]);
}

// fragment pointer: A-operand for tile ct, k-chunk kc, lane (quad,m16)
// = Wt[p][j = ct*16+m16][k = kc*32 + quad*8 .. +8]
static __device__ __forceinline__ const bf16x8* wfrag(
    const unsigned short* Wt, int p, int ct, int kc, int quad, int m16)
{
    return (const bf16x8*)(Wt + (size_t)p * 16384 +
                           (size_t)(ct * 16 + m16) * 128 + kc * 32 + quad * 8);
}

// ---------------------------------------------------------------------------
// K1 (role-split, NO LDS): adjacency fill (blocks [0,Nfill); 2 threads/edge,
// 1 atomic each -- the round-1 form that measured 105 us at 77% occupancy)
// + GEMM-S blocks that stream x -> xb (bf16) and compute the
// adjacency-independent self term
//   out[row] = dropout_mask * (x @ W_s)     (fp32, stored into d_out)
// W_s fragments read per-MFMA from L2. Zero barriers, zero LDS -> fill
// blocks keep full residency and the streaming/MFMA work rides their idle
// issue slots.
// ---------------------------------------------------------------------------
__global__ __launch_bounds__(256, 4) void fill_gemmS(
    const float* __restrict__ x,
    const unsigned short* __restrict__ Wt,
    const float* __restrict__ drop_u,
    unsigned short* __restrict__ xb,
    float* __restrict__ out,
    const int* __restrict__ send, const int* __restrict__ recv,
    int* __restrict__ counts, int* __restrict__ adj,
    int N, int E, int Nfill)
{
    const int bid = blockIdx.x;
    if (bid < Nfill) {
        // ---- adjacency fill ----
        int t = bid * 256 + threadIdx.x;
        int e = t >> 1;
        if (e < E) {
            int v, src;
            if (t & 1) { v = recv[e];     src = send[e]; }   // fwd: x[send]->recv
            else       { v = N + send[e]; src = recv[e]; }   // bwd: x[recv]->send
            int pos = atomicAdd(counts + v, 1);
            if (pos < CAP) adj[(size_t)v * CAP + pos] = src;
        }
        return;
    }

    // ---- GEMM-S ----
    const int gb   = bid - Nfill;
    const int lane = threadIdx.x & 63;
    const int wave = threadIdx.x >> 6;
    const int quad = lane >> 4;
    const int m16  = lane & 15;
    const int row  = gb * 64 + wave * 16 + m16;
    const int rowc = (row < N) ? row : N - 1;    // clamp loads; stores guarded

    // x row loads (B-fragment layout: elems kc*32 + quad*8 .. +8)
    const float* xp = x + (size_t)rowc * D;
    fvec4 xlo[4], xhi[4];
#pragma unroll
    for (int kc = 0; kc < 4; ++kc) {
        xlo[kc] = *(const fvec4*)(xp + kc * 32 + quad * 8);
        xhi[kc] = *(const fvec4*)(xp + kc * 32 + quad * 8 + 4);
    }
    fvec4 u[8];
#pragma unroll
    for (int ct = 0; ct < 8; ++ct)
        u[ct] = *(const fvec4*)(drop_u + (size_t)rowc * D + ct * 16 + quad * 4);

    // pack to bf16 fragments + emit xb (gather pool for K2)
    bf16x8 xf[4];
#pragma unroll
    for (int kc = 0; kc < 4; ++kc) {
        uint4 xi;
        xi.x = pack_bf2(xlo[kc][0], xlo[kc][1]);
        xi.y = pack_bf2(xlo[kc][2], xlo[kc][3]);
        xi.z = pack_bf2(xhi[kc][0], xhi[kc][1]);
        xi.w = pack_bf2(xhi[kc][2], xhi[kc][3]);
        xf[kc] = __builtin_bit_cast(bf16x8, xi);
        // clamped duplicate rows write identical bytes -> benign
        *(uint4*)(xb + (size_t)rowc * D + kc * 32 + quad * 8) = xi;
    }

    f32x4 C[8];
#pragma unroll
    for (int ct = 0; ct < 8; ++ct) C[ct] = (f32x4){0.f, 0.f, 0.f, 0.f};

#pragma unroll
    for (int kc = 0; kc < 4; ++kc) {
#pragma unroll
        for (int ct = 0; ct < 8; ++ct) {
            bf16x8 wf = *wfrag(Wt, 0, ct, kc, quad, m16);
            C[ct] = __builtin_amdgcn_mfma_f32_16x16x32_bf16(
                wf, xf[kc], C[ct], 0, 0, 0);
        }
    }

    if (row < N) {
#pragma unroll
        for (int ct = 0; ct < 8; ++ct) {
            fvec4 r;
#pragma unroll
            for (int c = 0; c < 4; ++c)
                r[c] = C[ct][c] * ((u[ct][c] < 0.8f) ? 1.25f : 0.0f);
            *(fvec4*)(out + (size_t)row * D + ct * 16 + quad * 4) = r;
        }
    }
}

// ---------------------------------------------------------------------------
// K2 (NO LDS, zero barriers): in-register gather + 2-pass MFMA + self + relu.
//   C  = S_f @ W_f   (S_f gathered in-register, fp32 accum, one bf16 round)
//   C += S_b @ W_b
//   out = relu(C + out)        (out holds the K1 self term, fp32)
// Gather: lane (quad,m16) accumulates xb[src][quad's 32 elems] -- exactly
// the MFMA B-fragment layout. W fragments from L2 per-MFMA. Self-term loads
// issued before the last pass. Nontemporal on the out read/write
// (write-once/read-once; round 2 showed 3x write amplification when these
// lines contended with the gather stream in L2).
// ---------------------------------------------------------------------------
__global__ __launch_bounds__(256, 4) void gather_gemm(
    const unsigned short* __restrict__ xb,
    const unsigned short* __restrict__ Wt,
    const int* __restrict__ counts, const int* __restrict__ adj,
    float* __restrict__ out, int N)
{
    const int lane = threadIdx.x & 63;
    const int wave = threadIdx.x >> 6;
    const int quad = lane >> 4;
    const int m16  = lane & 15;
    const int row  = blockIdx.x * 64 + wave * 16 + m16;
    const int rowc = (row < N) ? row : N - 1;

    f32x4 C[8];
#pragma unroll
    for (int ct = 0; ct < 8; ++ct) C[ct] = (f32x4){0.f, 0.f, 0.f, 0.f};

    bf16x8 xf[4];

    // in-register gather of one direction's neighbor sum -> xf
    auto gather_dir = [&](int base) {
        float s[4][8];
#pragma unroll
        for (int kc = 0; kc < 4; ++kc)
#pragma unroll
            for (int i = 0; i < 8; ++i) s[kc][i] = 0.0f;

        const int cv = base + rowc;
        int deg = counts[cv];
        if (deg > CAP) deg = CAP;
        const int* ap = adj + (size_t)cv * CAP;

        auto accum = [&](int src) {
            const unsigned short* sp = xb + (size_t)src * D + quad * 8;
            uint4 v0 = *(const uint4*)(sp);
            uint4 v1 = *(const uint4*)(sp + 32);
            uint4 v2 = *(const uint4*)(sp + 64);
            uint4 v3 = *(const uint4*)(sp + 96);
            s[0][0] += bflo(v0.x); s[0][1] += bfhi(v0.x);
            s[0][2] += bflo(v0.y); s[0][3] += bfhi(v0.y);
            s[0][4] += bflo(v0.z); s[0][5] += bfhi(v0.z);
            s[0][6] += bflo(v0.w); s[0][7] += bfhi(v0.w);
            s[1][0] += bflo(v1.x); s[1][1] += bfhi(v1.x);
            s[1][2] += bflo(v1.y); s[1][3] += bfhi(v1.y);
            s[1][4] += bflo(v1.z); s[1][5] += bfhi(v1.z);
            s[1][6] += bflo(v1.w); s[1][7] += bfhi(v1.w);
            s[2][0] += bflo(v2.x); s[2][1] += bfhi(v2.x);
            s[2][2] += bflo(v2.y); s[2][3] += bfhi(v2.y);
            s[2][4] += bflo(v2.z); s[2][5] += bfhi(v2.z);
            s[2][6] += bflo(v2.w); s[2][7] += bfhi(v2.w);
            s[3][0] += bflo(v3.x); s[3][1] += bfhi(v3.x);
            s[3][2] += bflo(v3.y); s[3][3] += bfhi(v3.y);
            s[3][4] += bflo(v3.z); s[3][5] += bfhi(v3.z);
            s[3][6] += bflo(v3.w); s[3][7] += bfhi(v3.w);
        };

        // 2-deep prefetch of src indices breaks the ap->xb dependency chain
        int s0 = (0 < deg) ? ap[0] : 0;
        int s1 = (1 < deg) ? ap[1] : 0;
        int j = 0;
        while (__any(j < deg)) {
            int n0 = (j + 2 < deg) ? ap[j + 2] : 0;
            int n1 = (j + 3 < deg) ? ap[j + 3] : 0;
            if (j < deg)     accum(s0);
            if (j + 1 < deg) accum(s1);
            s0 = n0; s1 = n1;
            j += 2;
        }

#pragma unroll
        for (int kc = 0; kc < 4; ++kc) {
            uint4 p;
            p.x = pack_bf2(s[kc][0], s[kc][1]);
            p.y = pack_bf2(s[kc][2], s[kc][3]);
            p.z = pack_bf2(s[kc][4], s[kc][5]);
            p.w = pack_bf2(s[kc][6], s[kc][7]);
            xf[kc] = __builtin_bit_cast(bf16x8, p);
        }
    };

    auto mfma_pass = [&](int p) {
#pragma unroll
        for (int kc = 0; kc < 4; ++kc) {
#pragma unroll
            for (int ct = 0; ct < 8; ++ct) {
                bf16x8 wf = *wfrag(Wt, p, ct, kc, quad, m16);
                C[ct] = __builtin_amdgcn_mfma_f32_16x16x32_bf16(
                    wf, xf[kc], C[ct], 0, 0, 0);
            }
        }
    };

    gather_dir(0);            // S_f -> xf
    mfma_pass(1);             // C = S_f @ W_f

    gather_dir(N);            // S_b -> xf

    // self-term loads: issue now, consumed after the last MFMA pass
    fvec4 t[8];
    if (row < N) {
#pragma unroll
        for (int ct = 0; ct < 8; ++ct)
            t[ct] = __builtin_nontemporal_load(
                (const fvec4*)(out + (size_t)row * D + ct * 16 + quad * 4));
    }

    mfma_pass(2);             // C += S_b @ W_b

    if (row < N) {
#pragma unroll
        for (int ct = 0; ct < 8; ++ct) {
            fvec4 r;
#pragma unroll
            for (int c = 0; c < 4; ++c)
                r[c] = fmaxf(C[ct][c] + t[ct][c], 0.0f);
            __builtin_nontemporal_store(
                r, (fvec4*)(out + (size_t)row * D + ct * 16 + quad * 4));
        }
    }
}

extern "C" void kernel_launch(void* const* d_in, const int* in_sizes, int n_in,
                              void* d_out, int out_size, void* d_ws, size_t ws_size,
                              hipStream_t stream)
{
    const float* x      = (const float*)d_in[0];
    const float* W_f    = (const float*)d_in[1];
    const float* W_b    = (const float*)d_in[2];
    const float* W_s    = (const float*)d_in[3];
    const float* drop_u = (const float*)d_in[4];
    const int*   send   = (const int*)d_in[5];
    const int*   recv   = (const int*)d_in[6];

    const int N = in_sizes[0] / D;   // 100000
    const int E = in_sizes[5];       // 600000

    float* out = (float*)d_out;

    // workspace layout (16B-aligned chunks):
    //   Wt     : 3*128*128 bf16 (96 KB, transposed, L2-resident)
    //   xb     : N*128 bf16   (25.6 MB)  x in bf16 (gather pool)
    //   counts : 2N ints      (0.8 MB)   fwd at [0,N), bwd at [N,2N)
    //   adj    : 2N*CAP ints  (25.6 MB)
    // Self term lives in d_out (written by K1, consumed+overwritten by K2).
    unsigned short* Wt = (unsigned short*)d_ws;
    unsigned short* xb = Wt + (size_t)3 * 128 * 128;
    int* counts = (int*)(xb + (size_t)N * D);
    int* adj    = counts + (size_t)2 * N;

    const int Nfill = (2 * E + 255) / 256;            // 4688 fill blocks
    const int Nb    = (N + 63) / 64;                  // 1563 GEMM blocks

    // P0: transposed W prep (tiny)
    prep_w<<<(3 * 128 * 128 + 255) / 256, 256, 0, stream>>>(W_f, W_b, W_s, Wt);

    // counts must start at zero (ws is poisoned each call)
    hipMemsetAsync(counts, 0, (size_t)2 * N * sizeof(int), stream);

    // K1: adjacency fill (first) overlapped with self-term GEMM + xb convert
    fill_gemmS<<<Nfill + Nb, 256, 0, stream>>>(
        x, Wt, drop_u, xb, out, send, recv, counts, adj, N, E, Nfill);

    // K2: gather + 2-pass GEMM + self add + relu -> out
    gather_gemm<<<Nb, 256, 0, stream>>>(xb, Wt, counts, adj, out, N);
}

// Round 5
// 369.991 us; speedup vs baseline: 1.0033x; 1.0033x over previous
//
#include <hip/hip_runtime.h>

typedef float fvec4 __attribute__((ext_vector_type(4)));
typedef float f32x4 __attribute__((ext_vector_type(4)));
typedef short bf16x8 __attribute__((ext_vector_type(8)));

#define D   128   // D_IN == D_OUT
#define CAP 32    // per-direction adjacency slots (deg ~ Poisson(6), max ~25)

static __device__ __forceinline__ unsigned bcu(float f) {
    return __builtin_bit_cast(unsigned, f);
}
// pack two fp32 (round-half-up to bf16) into one u32 (lo elem in low half)
static __device__ __forceinline__ unsigned pack_bf2(float f0, float f1) {
    unsigned a0 = bcu(f0) + 0x8000u;
    unsigned a1 = bcu(f1) + 0x8000u;
    return __builtin_amdgcn_perm(a1, a0, 0x07060302u);
}
// full-precision RNE for the (tiny) weight prep
static __device__ __forceinline__ unsigned short f2bf_rne(float f) {
    unsigned u = bcu(f);
    u += 0x7FFFu + ((u >> 16) & 1u);
    return (unsigned short)(u >> 16);
}
static __device__ __forceinline__ float bflo(unsigned u) {
    return __builtin_bit_cast(float, u << 16);
}
static __device__ __forceinline__ float bfhi(unsigned u) {
    return __builtin_bit_cast(float, u & 0xFFFF0000u);
}

#define NW_BLOCKS 192           // 192*256 = 49152 = 3*128*128 weight elems
#define CNT_PAD   200704        // 196*1024 ints (>= 2N=200000), zeroed exactly

// ---------------------------------------------------------------------------
// P0 (fused): transposed weight triple Wt (bf16) + counts zeroing.
// Blocks [0,NW): Wt[p][j][k] = W_p[k][j] (j = output col, k = input row);
// p=0 -> W_s, p=1 -> W_f, p=2 -> W_b.
// Blocks [NW,...): zero the (padded) counts region, int4 stores.
// Folding the memset here saves one dispatch.
// ---------------------------------------------------------------------------
__global__ __launch_bounds__(256) void prep_w(
    const float* __restrict__ Wf, const float* __restrict__ Wb,
    const float* __restrict__ Ws, unsigned short* __restrict__ Wt,
    int* __restrict__ counts)
{
    const int bid = blockIdx.x;
    if (bid < NW_BLOCKS) {
        int t = bid * 256 + threadIdx.x;
        int p = t >> 14;
        int e = t & 16383;
        int j = e >> 7;
        int k = e & 127;
        const float* W = (p == 0) ? Ws : (p == 1) ? Wf : Wb;
        Wt[t] = f2bf_rne(W[k * D + j]);
        return;
    }
    int zi = (bid - NW_BLOCKS) * 1024 + threadIdx.x * 4;   // < CNT_PAD exactly
    *(int4*)(counts + zi) = (int4){0, 0, 0, 0};
}

// fragment pointer: A-operand for tile ct, k-chunk kc, lane (quad,m16)
// = Wt[p][j = ct*16+m16][k = kc*32 + quad*8 .. +8]
static __device__ __forceinline__ const bf16x8* wfrag(
    const unsigned short* Wt, int p, int ct, int kc, int quad, int m16)
{
    return (const bf16x8*)(Wt + (size_t)p * 16384 +
                           (size_t)(ct * 16 + m16) * 128 + kc * 32 + quad * 8);
}

// ---------------------------------------------------------------------------
// K1: EXACT round-1 conv_fill (measured 105 us standalone, 77% occupancy).
// Blocks [0,Nfill): 2 threads/edge, 1 atomic each.
//   counter v      = fwd dest (recv, src = send)
//   counter N + v  = bwd dest (send, src = recv)
// Blocks [Nfill,...): x -> bf16 convert (8 floats/thread), nontemporal x
// reads (read-once; keep L2 for the adjacency traffic).
// NO GEMM here: rounds 3-4 proved co-scheduled GEMM-S gains nothing -- the
// self term now costs one extra MFMA pass in K2 instead of a 153 MB
// out-write/read/rewrite round-trip.
// ---------------------------------------------------------------------------
__global__ __launch_bounds__(256) void conv_fill(
    const float* __restrict__ x, unsigned short* __restrict__ xb,
    const int* __restrict__ send, const int* __restrict__ recv,
    int* __restrict__ counts, int* __restrict__ adj,
    int N, int E, int Nfill)
{
    const int bid = blockIdx.x;
    if (bid < Nfill) {
        int t = bid * 256 + threadIdx.x;
        int e = t >> 1;
        if (e < E) {
            int v, src;
            if (t & 1) { v = recv[e];     src = send[e]; }   // fwd: x[send]->recv
            else       { v = N + send[e]; src = recv[e]; }   // bwd: x[recv]->send
            int pos = atomicAdd(counts + v, 1);
            if (pos < CAP) adj[(size_t)v * CAP + pos] = src;
        }
        return;
    }
    // convert: 8 floats / thread
    size_t base = ((size_t)(bid - Nfill) * 256 + threadIdx.x) * 8;
    if (base >= (size_t)N * D) return;
    fvec4 a = __builtin_nontemporal_load((const fvec4*)(x + base));
    fvec4 b = __builtin_nontemporal_load((const fvec4*)(x + base + 4));
    uint4 p;
    p.x = pack_bf2(a[0], a[1]);
    p.y = pack_bf2(a[2], a[3]);
    p.z = pack_bf2(b[0], b[1]);
    p.w = pack_bf2(b[2], b[3]);
    *(uint4*)(xb + base) = p;   // re-read by K2 -> keep cacheable
}

// ---------------------------------------------------------------------------
// K2: in-register gather + 3-pass MFMA + dropout + relu -> out. No LDS,
// zero barriers (max residency for the latency-bound gather).
//   pass0: C  = xb[row] @ W_s   (own row: contiguous, L3-warm)
//   mask:  C *= dropout         (drop_u nontemporal, read-once)
//   pass1: C += S_f @ W_f       (S_f gathered in-register)
//   pass2: C += S_b @ W_b
// Gather: lane (quad,m16) accumulates xb[src][quad's 32 elems] -- exactly
// the MFMA B-fragment layout -- fp32 accum, one bf16 round. W fragments
// straight from L2 (Wt = 96 KB, chip-hot). Nontemporal out stores
// (write-once; round-2 showed 3x write amplification without this).
// ---------------------------------------------------------------------------
__global__ __launch_bounds__(256, 4) void gather_gemm3(
    const unsigned short* __restrict__ xb,
    const unsigned short* __restrict__ Wt,
    const float* __restrict__ drop_u,
    const int* __restrict__ counts, const int* __restrict__ adj,
    float* __restrict__ out, int N)
{
    const int lane = threadIdx.x & 63;
    const int wave = threadIdx.x >> 6;
    const int quad = lane >> 4;
    const int m16  = lane & 15;
    const int row  = blockIdx.x * 64 + wave * 16 + m16;
    const int rowc = (row < N) ? row : N - 1;

    f32x4 C[8];
#pragma unroll
    for (int ct = 0; ct < 8; ++ct) C[ct] = (f32x4){0.f, 0.f, 0.f, 0.f};

    bf16x8 xf[4];

    auto mfma_pass = [&](int p) {
#pragma unroll
        for (int kc = 0; kc < 4; ++kc) {
#pragma unroll
            for (int ct = 0; ct < 8; ++ct) {
                bf16x8 wf = *wfrag(Wt, p, ct, kc, quad, m16);
                C[ct] = __builtin_amdgcn_mfma_f32_16x16x32_bf16(
                    wf, xf[kc], C[ct], 0, 0, 0);
            }
        }
    };

    // ---- pass 0: self term ----
    const unsigned short* xp = xb + (size_t)rowc * D;
#pragma unroll
    for (int kc = 0; kc < 4; ++kc)
        xf[kc] = *(const bf16x8*)(xp + kc * 32 + quad * 8);
    fvec4 u[8];
#pragma unroll
    for (int ct = 0; ct < 8; ++ct)
        u[ct] = __builtin_nontemporal_load(
            (const fvec4*)(drop_u + (size_t)rowc * D + ct * 16 + quad * 4));

    mfma_pass(0);             // C = x @ W_s
#pragma unroll
    for (int ct = 0; ct < 8; ++ct) {
#pragma unroll
        for (int c = 0; c < 4; ++c)
            C[ct][c] *= (u[ct][c] < 0.8f) ? 1.25f : 0.0f;
    }

    // in-register gather of one direction's neighbor sum -> xf
    auto gather_dir = [&](int base) {
        float s[4][8];
#pragma unroll
        for (int kc = 0; kc < 4; ++kc)
#pragma unroll
            for (int i = 0; i < 8; ++i) s[kc][i] = 0.0f;

        const int cv = base + rowc;
        int deg = counts[cv];
        if (deg > CAP) deg = CAP;
        const int* ap = adj + (size_t)cv * CAP;

        auto accum = [&](int src) {
            const unsigned short* sp = xb + (size_t)src * D + quad * 8;
            uint4 v0 = *(const uint4*)(sp);
            uint4 v1 = *(const uint4*)(sp + 32);
            uint4 v2 = *(const uint4*)(sp + 64);
            uint4 v3 = *(const uint4*)(sp + 96);
            s[0][0] += bflo(v0.x); s[0][1] += bfhi(v0.x);
            s[0][2] += bflo(v0.y); s[0][3] += bfhi(v0.y);
            s[0][4] += bflo(v0.z); s[0][5] += bfhi(v0.z);
            s[0][6] += bflo(v0.w); s[0][7] += bfhi(v0.w);
            s[1][0] += bflo(v1.x); s[1][1] += bfhi(v1.x);
            s[1][2] += bflo(v1.y); s[1][3] += bfhi(v1.y);
            s[1][4] += bflo(v1.z); s[1][5] += bfhi(v1.z);
            s[1][6] += bflo(v1.w); s[1][7] += bfhi(v1.w);
            s[2][0] += bflo(v2.x); s[2][1] += bfhi(v2.x);
            s[2][2] += bflo(v2.y); s[2][3] += bfhi(v2.y);
            s[2][4] += bflo(v2.z); s[2][5] += bfhi(v2.z);
            s[2][6] += bflo(v2.w); s[2][7] += bfhi(v2.w);
            s[3][0] += bflo(v3.x); s[3][1] += bfhi(v3.x);
            s[3][2] += bflo(v3.y); s[3][3] += bfhi(v3.y);
            s[3][4] += bflo(v3.z); s[3][5] += bfhi(v3.z);
            s[3][6] += bflo(v3.w); s[3][7] += bfhi(v3.w);
        };

        // 2-deep prefetch of src indices breaks the ap->xb dependency chain
        int s0 = (0 < deg) ? ap[0] : 0;
        int s1 = (1 < deg) ? ap[1] : 0;
        int j = 0;
        while (__any(j < deg)) {
            int n0 = (j + 2 < deg) ? ap[j + 2] : 0;
            int n1 = (j + 3 < deg) ? ap[j + 3] : 0;
            if (j < deg)     accum(s0);
            if (j + 1 < deg) accum(s1);
            s0 = n0; s1 = n1;
            j += 2;
        }

#pragma unroll
        for (int kc = 0; kc < 4; ++kc) {
            uint4 p;
            p.x = pack_bf2(s[kc][0], s[kc][1]);
            p.y = pack_bf2(s[kc][2], s[kc][3]);
            p.z = pack_bf2(s[kc][4], s[kc][5]);
            p.w = pack_bf2(s[kc][6], s[kc][7]);
            xf[kc] = __builtin_bit_cast(bf16x8, p);
        }
    };

    gather_dir(0);            // S_f -> xf
    mfma_pass(1);             // C += S_f @ W_f

    gather_dir(N);            // S_b -> xf
    mfma_pass(2);             // C += S_b @ W_b

    if (row < N) {
#pragma unroll
        for (int ct = 0; ct < 8; ++ct) {
            fvec4 r;
#pragma unroll
            for (int c = 0; c < 4; ++c)
                r[c] = fmaxf(C[ct][c], 0.0f);
            __builtin_nontemporal_store(
                r, (fvec4*)(out + (size_t)row * D + ct * 16 + quad * 4));
        }
    }
}

extern "C" void kernel_launch(void* const* d_in, const int* in_sizes, int n_in,
                              void* d_out, int out_size, void* d_ws, size_t ws_size,
                              hipStream_t stream)
{
    const float* x      = (const float*)d_in[0];
    const float* W_f    = (const float*)d_in[1];
    const float* W_b    = (const float*)d_in[2];
    const float* W_s    = (const float*)d_in[3];
    const float* drop_u = (const float*)d_in[4];
    const int*   send   = (const int*)d_in[5];
    const int*   recv   = (const int*)d_in[6];

    const int N = in_sizes[0] / D;   // 100000
    const int E = in_sizes[5];       // 600000

    float* out = (float*)d_out;

    // workspace layout (16B-aligned chunks):
    //   Wt     : 3*128*128 bf16 (96 KB, transposed, L2-hot)
    //   xb     : N*128 bf16   (25.6 MB)  x in bf16 (gather pool)
    //   counts : CNT_PAD ints (0.8 MB)   fwd at [0,N), bwd at [N,2N)
    //   adj    : 2N*CAP ints  (25.6 MB)
    unsigned short* Wt = (unsigned short*)d_ws;
    unsigned short* xb = Wt + (size_t)3 * 128 * 128;
    int* counts = (int*)(xb + (size_t)N * D);
    int* adj    = counts + CNT_PAD;

    const int Nzero = (CNT_PAD + 1023) / 1024;        // 196 zero blocks
    const int Nfill = (2 * E + 255) / 256;            // 4688 fill blocks
    const int Nconv = (N * D + 2047) / 2048;          // 6250 convert blocks
    const int Nb    = (N + 63) / 64;                  // 1563 GEMM blocks

    // P0: transposed W prep + counts zeroing (one dispatch)
    prep_w<<<NW_BLOCKS + Nzero, 256, 0, stream>>>(W_f, W_b, W_s, Wt, counts);

    // K1: adjacency fill + x->bf16 convert (round-1 form, 105 us standalone)
    conv_fill<<<Nfill + Nconv, 256, 0, stream>>>(x, xb, send, recv,
                                                 counts, adj, N, E, Nfill);

    // K2: gather + 3-pass GEMM + dropout + relu -> out
    gather_gemm3<<<Nb, 256, 0, stream>>>(xb, Wt, drop_u, counts, adj, out, N);
}